// Round 3
// baseline (165.026 us; speedup 1.0000x reference)
//
#include <hip/hip_runtime.h>

#define HW (512*512)

typedef __attribute__((ext_vector_type(8))) short bfrag;   // 8 x bf16
typedef __attribute__((ext_vector_type(4))) float ffrag;   // 4 x f32 acc
typedef __attribute__((ext_vector_type(4))) float fx4;

__device__ __forceinline__ unsigned short f2bf(float f) {
  unsigned int u = __float_as_uint(f);
  u += 0x7fffu + ((u >> 16) & 1u);        // round-to-nearest-even
  return (unsigned short)(u >> 16);
}
__device__ __forceinline__ unsigned int pk2(float a, float b) {
  return (unsigned int)f2bf(a) | ((unsigned int)f2bf(b) << 16);
}

// ---------- Kernel W: pack conv weights into MFMA A-fragment layout --------
// Fragment (ciblk, tap): lane l holds W[co = l&15][ci = ciblk*32 + (l>>4)*8 + j]
__global__ __launch_bounds__(256) void pack_w_k(
    const float* __restrict__ cw, unsigned short* __restrict__ wp) {
  int gid = blockIdx.x * 256 + threadIdx.x;
  if (gid >= 72 * 64) return;
  int fid = gid >> 6, lane = gid & 63;
  int cib = fid / 9, tap = fid - cib * 9;
  int g = lane >> 4, m = lane & 15;
  unsigned short v[8];
#pragma unroll
  for (int j = 0; j < 8; ++j) {
    int ci = cib * 32 + g * 8 + j;
    float f = (m < 8) ? cw[(m * 256 + ci) * 9 + tap] : 0.0f;
    v[j] = f2bf(f);
  }
  *(uint4*)(wp + gid * 8) = *(const uint4*)v;
}

// ---------------- Kernel A: 3x3 conv via bf16 MFMA implicit GEMM -----------
// 32w x 16h tile, 512 blocks, 4 waves. T14 async-split staging:
// issue loads(t+1) -> MFMA on buf[t] -> convert+ds_write -> barrier.
constexpr int SROW = 34, NR = 18, SPIX = SROW * NR;       // 612
constexpr int GSTRIDE = SPIX * 16;                         // 9792 B per kgroup
constexpr int BUF_BYTES = 4 * GSTRIDE;                     // 39168 B

__global__ __launch_bounds__(256, 2) void conv_mfma_k(
    const float* __restrict__ x, const unsigned short* __restrict__ wp,
    const float* __restrict__ cb, float* __restrict__ xc) {
  __shared__ __align__(16) char xs[2 * BUF_BYTES];
  const int tid  = threadIdx.x;
  const int wv   = tid >> 6, lane = tid & 63;
  const int g    = lane >> 4, p = lane & 15;
  const int bw   = blockIdx.x & 15, bh = blockIdx.x >> 4;
  const int w0   = bw * 32, h0 = bh * 16;

  // ---- t-invariant staging descriptors (computed once) ----
  // body: 1024 units = 8 cig x 16 row x 8 chunk4; always in-range
  int b_goff[4], b_loff[4], b_plane[4];
#pragma unroll
  for (int i = 0; i < 4; ++i) {
    int u = tid + 256 * i;
    int cig = u >> 7, row = (u >> 3) & 15, chunk = u & 7;
    b_goff[i]  = (h0 + row) * 512 + w0 + chunk * 4;
    b_loff[i]  = (cig >> 1) * GSTRIDE + ((row + 1) * SROW + chunk * 4 + 1) * 16
               + (cig & 1) * 8;
    b_plane[i] = cig * 4;
  }
  // halo: 800 units = 100 px x 8 cig (ring of width 1)
  int h_goff[4], h_loff[4], h_plane[4];
  bool h_ok[4], h_act[4];
#pragma unroll
  for (int i = 0; i < 4; ++i) {
    int u = tid + 256 * i;
    h_act[i] = (u < 800);
    int px = u >> 3, cig = u & 7;
    int r, c;
    if (px < 34)      { r = 0;  c = px; }
    else if (px < 68) { r = 17; c = px - 34; }
    else if (px < 84) { r = 1 + (px - 68); c = 0; }
    else              { r = 1 + (px - 84); c = 33; }
    int gh = h0 - 1 + r, gw = w0 - 1 + c;
    h_ok[i]    = h_act[i] && (unsigned)gh < 512u && (unsigned)gw < 512u;
    h_goff[i]  = gh * 512 + gw;
    h_loff[i]  = (cig >> 1) * GSTRIDE + (r * SROW + c) * 16 + (cig & 1) * 8;
    h_plane[i] = cig * 4;
  }

  fx4  bf[4][4];   // [unit][plane] in-flight body data
  float hf[4][4];  // [unit][plane] in-flight halo data

  auto issue_loads = [&](int t) {
    const float* xb = x + (size_t)t * 32 * HW;
#pragma unroll
    for (int i = 0; i < 4; ++i) {
      const float* pb = xb + (size_t)b_plane[i] * HW + b_goff[i];
#pragma unroll
      for (int pl = 0; pl < 4; ++pl)
        bf[i][pl] = *(const fx4*)(pb + (size_t)pl * HW);
    }
#pragma unroll
    for (int i = 0; i < 4; ++i) {
      const float* pb = xb + (size_t)h_plane[i] * HW + h_goff[i];
#pragma unroll
      for (int pl = 0; pl < 4; ++pl)
        hf[i][pl] = h_ok[i] ? pb[(size_t)pl * HW] : 0.0f;
    }
  };

  auto write_lds = [&](int t) {
    char* dst = xs + (t & 1) * BUF_BYTES;
#pragma unroll
    for (int i = 0; i < 4; ++i)
#pragma unroll
      for (int k = 0; k < 4; ++k) {
        uint2 v;
        v.x = pk2(bf[i][0][k], bf[i][1][k]);
        v.y = pk2(bf[i][2][k], bf[i][3][k]);
        *(uint2*)(dst + b_loff[i] + k * 16) = v;
      }
#pragma unroll
    for (int i = 0; i < 4; ++i)
      if (h_act[i]) {
        uint2 v;
        v.x = pk2(hf[i][0], hf[i][1]);
        v.y = pk2(hf[i][2], hf[i][3]);
        *(uint2*)(dst + h_loff[i]) = v;
      }
  };

  ffrag acc[8];
#pragma unroll
  for (int i = 0; i < 8; ++i) acc[i] = ffrag{0.f, 0.f, 0.f, 0.f};

  issue_loads(0);
  write_lds(0);
  __syncthreads();

#pragma unroll 1
  for (int t = 0; t < 8; ++t) {
    // A fragments FIRST (so their vmcnt wait doesn't drain staging loads)
    bfrag a[9];
    const unsigned short* wpt = wp + (size_t)(t * 9) * 512 + lane * 8;
#pragma unroll
    for (int tap = 0; tap < 9; ++tap)
      a[tap] = *(const bfrag*)(wpt + tap * 512);

    if (t < 7) issue_loads(t + 1);   // in flight across the MFMA phase

    // MFMA phase on buf[t&1]: row-major, 36 ds_read_b128, 72 MFMA
    const char* base = xs + (t & 1) * BUF_BYTES + g * GSTRIDE + p * 16;
#pragma unroll
    for (int row = 0; row < 6; ++row) {
      bfrag br[2][3];
#pragma unroll
      for (int cg = 0; cg < 2; ++cg)
#pragma unroll
        for (int dx = 0; dx < 3; ++dx)
          br[cg][dx] = *(const bfrag*)(base +
              ((wv * 4 + row) * SROW + cg * 16 + dx) * 16);
#pragma unroll
      for (int r2 = 0; r2 < 4; ++r2) {
        const int dy = row - r2;
        if (dy >= 0 && dy <= 2) {
#pragma unroll
          for (int dx = 0; dx < 3; ++dx)
#pragma unroll
            for (int cg = 0; cg < 2; ++cg)
              acc[r2 * 2 + cg] = __builtin_amdgcn_mfma_f32_16x16x32_bf16(
                  a[dy * 3 + dx], br[cg][dx], acc[r2 * 2 + cg], 0, 0, 0);
        }
      }
    }

    if (t < 7) {
      write_lds(t + 1);              // vmcnt drain lands here, after compute
      __syncthreads();
    }
  }

  // epilogue: D col = lane&15 (pixel), row = (lane>>4)*4 + reg (co)
  if (lane < 32) {
#pragma unroll
    for (int r2 = 0; r2 < 4; ++r2)
#pragma unroll
      for (int cg = 0; cg < 2; ++cg) {
        const int h = h0 + wv * 4 + r2, wcol = w0 + cg * 16 + p;
#pragma unroll
        for (int reg = 0; reg < 4; ++reg) {
          int co = g * 4 + reg;
          xc[co * HW + h * 512 + wcol] = acc[r2 * 2 + cg][reg] + cb[co];
        }
      }
  }
}

// ------------- Kernel B: argmax one-hot -> 8x8 mean pool -> unfold ---------
__global__ __launch_bounds__(256) void argmax_pool_unfold_k(
    const float* __restrict__ xc, float* __restrict__ U) {
  const int lane = threadIdx.x & 63;
  const int wv   = threadIdx.x >> 6;
  const int cell = blockIdx.x * 4 + wv;      // 0..4095
  const int hd = cell >> 6, wd = cell & 63;  // fm coords (64x64)
  const int h = hd * 8 + (lane >> 3), w = wd * 8 + (lane & 7);
  const int pix = h * 512 + w;

  float best = xc[pix];
  int bc = 0;
#pragma unroll
  for (int c = 1; c < 8; ++c) {
    float v = xc[c * HW + pix];
    if (v > best) { best = v; bc = c; }
  }
  float myu = 0.f;
#pragma unroll
  for (int c = 0; c < 8; ++c) {
    unsigned long long mk = __ballot(bc == c);
    if (lane == c) myu = (float)__popcll(mk) * (1.0f / 64.0f);
  }
  if (lane < 8) {
    const int k = (hd & 7) * 8 + (wd & 7);   // kernel element
    const int m = (hd >> 3) * 8 + (wd >> 3); // patch position
    U[lane * 4096 + k * 64 + m] = myu;
  }
}

// ---- Kernel C: att=(A/nz)·U, fold, 1x1 conv, out=corr*x+x, + attn copy ----
__global__ __launch_bounds__(256) void att_fold_corr_k(
    const float* __restrict__ attn, const float* __restrict__ U,
    const float* __restrict__ cw, const float* __restrict__ cb,
    float* __restrict__ out, float* __restrict__ attn_out) {
  __shared__ float Ul[2][4096];
  __shared__ float Ar[4][64];
  const int tid  = threadIdx.x;
  const int lane = tid & 63;
  const int wv   = tid >> 6;
  const int l    = blockIdx.x * 4 + wv;
  const int hq = l >> 6, wq = l & 63;
  const int h = hq * 8 + (lane >> 3), w = wq * 8 + (lane & 7);

  // prologue: fill Ul[0] with U[c=0]
  for (int i = tid; i < 1024; i += 256)
    ((fx4*)Ul[0])[i] = ((const fx4*)U)[i];
  __syncthreads();

  float corrv[8];
#pragma unroll 1
  for (int c = 0; c < 8; ++c) {
    if (c < 7)
      for (int i = tid; i < 1024; i += 256)
        ((fx4*)Ul[(c + 1) & 1])[i] = ((const fx4*)(U + (c + 1) * 4096))[i];

    const int aidx = ((c << 12) + l) * 64 + lane;
    float av = attn[aidx];
    attn_out[aidx] = av;                      // output 1: verbatim copy
    unsigned long long nzm = __ballot(av != 0.0f);
    float inv = 1.0f / ((float)__popcll(nzm) + 1e-5f);
    Ar[wv][lane] = av * inv;

    const float* u = Ul[c & 1];
    float s = 0.f;
#pragma unroll
    for (int k = 0; k < 64; ++k)
      s = fmaf(Ar[wv][k], u[k * 64 + lane], s);
    corrv[c] = s;
    __syncthreads();   // compute(c) done before fill(c+2) overwrites Ul[c&1]
  }

  const int pix = h * 512 + w;
#pragma unroll
  for (int d = 0; d < 8; ++d) {
    float s = cb[d];
#pragma unroll
    for (int c = 0; c < 8; ++c)
      s = fmaf(corrv[c], cw[d * 8 + c], s);
    float v = out[d * HW + pix];
    out[d * HW + pix] = fmaf(s, v, v);
  }
}

extern "C" void kernel_launch(void* const* d_in, const int* in_sizes, int n_in,
                              void* d_out, int out_size, void* d_ws, size_t ws_size,
                              hipStream_t stream) {
  const float* x    = (const float*)d_in[0];
  const float* attn = (const float*)d_in[1];
  const float* cw   = (const float*)d_in[2];
  const float* cb   = (const float*)d_in[3];
  const float* qw   = (const float*)d_in[4];
  const float* qb   = (const float*)d_in[5];
  float* out = (float*)d_out;

  unsigned short* wpack = (unsigned short*)d_ws;          // 72 KB
  float* U  = (float*)((char*)d_ws + 73728);              // 128 KB
  float* xc = out;                                        // x_conv in out[0:2M]

  pack_w_k<<<dim3(18), dim3(256), 0, stream>>>(cw, wpack);
  conv_mfma_k<<<dim3(512), dim3(256), 0, stream>>>(x, wpack, cb, xc);
  argmax_pool_unfold_k<<<dim3(1024), dim3(256), 0, stream>>>(xc, U);
  att_fold_corr_k<<<dim3(1024), dim3(256), 0, stream>>>(attn, U, qw, qb,
                                                        out, out + 2097152);
}

// Round 4
// 162.230 us; speedup vs baseline: 1.0172x; 1.0172x over previous
//
#include <hip/hip_runtime.h>

#define HW (512*512)

typedef __attribute__((ext_vector_type(8))) short bfrag;   // 8 x bf16
typedef __attribute__((ext_vector_type(4))) float ffrag;   // 4 x f32 acc
typedef __attribute__((ext_vector_type(4))) float fx4;
typedef __attribute__((ext_vector_type(4))) unsigned int ux4;

__device__ __forceinline__ unsigned short f2bf(float f) {
  unsigned int u = __float_as_uint(f);
  u += 0x7fffu + ((u >> 16) & 1u);        // round-to-nearest-even
  return (unsigned short)(u >> 16);
}
__device__ __forceinline__ unsigned int pk2(float a, float b) {
  return (unsigned int)f2bf(a) | ((unsigned int)f2bf(b) << 16);
}

// ---------- Kernel W: pack conv weights into MFMA A-fragment layout --------
// Fragment (ciblk, tap): lane l holds W[co = l&15][ci = ciblk*32 + (l>>4)*8 + j]
__global__ __launch_bounds__(256) void pack_w_k(
    const float* __restrict__ cw, unsigned short* __restrict__ wp) {
  int gid = blockIdx.x * 256 + threadIdx.x;
  if (gid >= 72 * 64) return;
  int fid = gid >> 6, lane = gid & 63;
  int cib = fid / 9, tap = fid - cib * 9;
  int g = lane >> 4, m = lane & 15;
  unsigned short v[8];
#pragma unroll
  for (int j = 0; j < 8; ++j) {
    int ci = cib * 32 + g * 8 + j;
    float f = (m < 8) ? cw[(m * 256 + ci) * 9 + tap] : 0.0f;
    v[j] = f2bf(f);
  }
  *(uint4*)(wp + gid * 8) = *(const uint4*)v;
}

// ---------------- Kernel A: 3x3 conv via bf16 MFMA implicit GEMM -----------
// 32w x 16h tile, 512 threads (8 waves of 16w x 4h), 512 blocks.
// Single 39KB LDS buffer [kgrp4][pix 18*34][8ci x bf16]; register prefetch of
// tile t+1 held in named fx4 regs across the MFMA phase (no lambdas/arrays).
constexpr int SROW = 34;
constexpr int GS = 612 * 16;               // 9792 B per ci-group of 8
// staging unit u (0..719): seg = u%10, g = (u/10)&3, r = u/40
// covers px -4..35 of staged row r as 10 aligned fx4 per 8-plane group.

__global__ __launch_bounds__(512, 2) void conv_mfma_k(
    const float* __restrict__ x, const unsigned short* __restrict__ wp,
    const float* __restrict__ cb, float* __restrict__ xc) {
  __shared__ __align__(16) char xs[4 * GS];              // 39168 B
  const int tid  = threadIdx.x;
  const int wid  = tid >> 6, lane = tid & 63;
  const int gl   = lane >> 4, p = lane & 15;
  const int wcol = wid & 1, hrow = wid >> 1;
  const int bw = blockIdx.x & 15, bh = blockIdx.x >> 4;
  const int w0 = bw * 32, h0 = bh * 16;

  // ---- t-invariant descriptors for my two staging units ----
  int goff0, pg0, ldsb0, dm0 = 0, wm0 = 0;
  int goff1, pg1, ldsb1, dm1 = 0, wm1 = 0;
  const bool act1 = (tid < 208);
  {
    int u = tid;
    int seg = u % 10, v = u / 10, g = v & 3, r = v >> 2;
    int gh = h0 - 1 + r;
    int gw0 = w0 - 4 + seg * 4;
    bool vh = (unsigned)gh < 512u;
    goff0 = min(max(gh, 0), 511) * 512 + min(max(gw0, 0), 508);
    pg0   = g * 8;
    ldsb0 = g * GS + (r * SROW + seg * 4 - 3) * 16;
#pragma unroll
    for (int j = 0; j < 4; ++j) {
      if (vh && (unsigned)(gw0 + j) < 512u) dm0 |= 1 << j;
      int c = seg * 4 - 3 + j;
      if ((unsigned)c < 34u) wm0 |= 1 << j;
    }
  }
  {
    int u = tid + 512;
    int seg = u % 10, v = u / 10, g = v & 3, r = v >> 2;
    int gh = h0 - 1 + r;
    int gw0 = w0 - 4 + seg * 4;
    bool vh = act1 && ((unsigned)gh < 512u);
    goff1 = min(max(gh, 0), 511) * 512 + min(max(gw0, 0), 508);
    pg1   = g * 8;
    ldsb1 = g * GS + (r * SROW + seg * 4 - 3) * 16;
#pragma unroll
    for (int j = 0; j < 4; ++j) {
      if (vh && (unsigned)(gw0 + j) < 512u) dm1 |= 1 << j;
      int c = seg * 4 - 3 + j;
      if (act1 && (unsigned)c < 34u) wm1 |= 1 << j;
    }
  }

  // in-flight staging registers (named, straight-line)
  fx4 A0, A1, A2, A3, A4, A5, A6, A7;
  fx4 B0, B1, B2, B3, B4, B5, B6, B7;

#define ISSUE(t)                                                            \
  {                                                                         \
    const float* p0 = x + (size_t)((t) * 32 + pg0) * HW + goff0;            \
    A0 = *(const fx4*)(p0);          A1 = *(const fx4*)(p0 + HW);           \
    A2 = *(const fx4*)(p0 + 2*HW);   A3 = *(const fx4*)(p0 + 3*HW);         \
    A4 = *(const fx4*)(p0 + 4*HW);   A5 = *(const fx4*)(p0 + 5*HW);         \
    A6 = *(const fx4*)(p0 + 6*HW);   A7 = *(const fx4*)(p0 + 7*HW);         \
    if (act1) {                                                             \
      const float* p1 = x + (size_t)((t) * 32 + pg1) * HW + goff1;          \
      B0 = *(const fx4*)(p1);          B1 = *(const fx4*)(p1 + HW);         \
      B2 = *(const fx4*)(p1 + 2*HW);   B3 = *(const fx4*)(p1 + 3*HW);       \
      B4 = *(const fx4*)(p1 + 4*HW);   B5 = *(const fx4*)(p1 + 5*HW);       \
      B6 = *(const fx4*)(p1 + 6*HW);   B7 = *(const fx4*)(p1 + 7*HW);       \
    }                                                                       \
  }

#define WRITE_UNIT(ldsb, dm, wm, V0, V1, V2, V3, V4, V5, V6, V7)            \
  _Pragma("unroll")                                                         \
  for (int j = 0; j < 4; ++j) {                                            \
    ux4 pk;                                                                 \
    pk.x = pk2(V0[j], V1[j]); pk.y = pk2(V2[j], V3[j]);                     \
    pk.z = pk2(V4[j], V5[j]); pk.w = pk2(V6[j], V7[j]);                     \
    if (!((dm) & (1 << j))) { pk.x = 0; pk.y = 0; pk.z = 0; pk.w = 0; }     \
    if ((wm) & (1 << j)) *(ux4*)(xs + (ldsb) + j * 16) = pk;                \
  }

  ffrag acc0 = {0,0,0,0}, acc1 = {0,0,0,0}, acc2 = {0,0,0,0}, acc3 = {0,0,0,0};

  ISSUE(0);
  WRITE_UNIT(ldsb0, dm0, wm0, A0, A1, A2, A3, A4, A5, A6, A7);
  WRITE_UNIT(ldsb1, dm1, wm1, B0, B1, B2, B3, B4, B5, B6, B7);
  __syncthreads();

  const char* rbase = xs + gl * GS + (hrow * 4 * SROW + wcol * 16 + p) * 16;

#pragma unroll 1
  for (int t = 0; t < 8; ++t) {
    // A fragments first (vmcnt wait for them won't drain staging loads)
    bfrag a[9];
    const unsigned short* wpt = wp + (size_t)(t * 9) * 512 + lane * 8;
#pragma unroll
    for (int tap = 0; tap < 9; ++tap)
      a[tap] = *(const bfrag*)(wpt + tap * 512);

    if (t < 7) ISSUE(t + 1);      // 16 fx4 in flight across the MFMA phase

    // MFMA phase: 18 ds_read_b128 + 36 MFMA
#pragma unroll
    for (int row6 = 0; row6 < 6; ++row6) {
#pragma unroll
      for (int dx = 0; dx < 3; ++dx) {
        bfrag b = *(const bfrag*)(rbase + (row6 * SROW + dx) * 16);
        if (row6 - 0 >= 0 && row6 - 0 <= 2)
          acc0 = __builtin_amdgcn_mfma_f32_16x16x32_bf16(a[(row6-0)*3+dx], b, acc0, 0,0,0);
        if (row6 - 1 >= 0 && row6 - 1 <= 2)
          acc1 = __builtin_amdgcn_mfma_f32_16x16x32_bf16(a[(row6-1)*3+dx], b, acc1, 0,0,0);
        if (row6 - 2 >= 0 && row6 - 2 <= 2)
          acc2 = __builtin_amdgcn_mfma_f32_16x16x32_bf16(a[(row6-2)*3+dx], b, acc2, 0,0,0);
        if (row6 - 3 >= 0 && row6 - 3 <= 2)
          acc3 = __builtin_amdgcn_mfma_f32_16x16x32_bf16(a[(row6-3)*3+dx], b, acc3, 0,0,0);
      }
    }

    __syncthreads();              // all waves done reading before overwrite
    if (t < 7) {
      WRITE_UNIT(ldsb0, dm0, wm0, A0, A1, A2, A3, A4, A5, A6, A7);
      WRITE_UNIT(ldsb1, dm1, wm1, B0, B1, B2, B3, B4, B5, B6, B7);
      __syncthreads();
    }
  }
#undef ISSUE
#undef WRITE_UNIT

  // epilogue: D col = lane&15 (pixel), row = (lane>>4)*4 + reg (co)
  if (lane < 32) {
    const int wcolp = w0 + wcol * 16 + p;
#pragma unroll
    for (int reg = 0; reg < 4; ++reg) {
      int co = gl * 4 + reg;
      float b = cb[co];
      float* o = xc + co * HW + (h0 + hrow * 4) * 512 + wcolp;
      o[0]       = acc0[reg] + b;
      o[512]     = acc1[reg] + b;
      o[1024]    = acc2[reg] + b;
      o[1536]    = acc3[reg] + b;
    }
  }
}

// ------------- Kernel B: argmax one-hot -> 8x8 mean pool -> unfold ---------
__global__ __launch_bounds__(256) void argmax_pool_unfold_k(
    const float* __restrict__ xc, float* __restrict__ U) {
  const int lane = threadIdx.x & 63;
  const int wv   = threadIdx.x >> 6;
  const int cell = blockIdx.x * 4 + wv;      // 0..4095
  const int hd = cell >> 6, wd = cell & 63;  // fm coords (64x64)
  const int h = hd * 8 + (lane >> 3), w = wd * 8 + (lane & 7);
  const int pix = h * 512 + w;

  float best = xc[pix];
  int bc = 0;
#pragma unroll
  for (int c = 1; c < 8; ++c) {
    float v = xc[c * HW + pix];
    if (v > best) { best = v; bc = c; }
  }
  float myu = 0.f;
#pragma unroll
  for (int c = 0; c < 8; ++c) {
    unsigned long long mk = __ballot(bc == c);
    if (lane == c) myu = (float)__popcll(mk) * (1.0f / 64.0f);
  }
  if (lane < 8) {
    const int k = (hd & 7) * 8 + (wd & 7);   // kernel element
    const int m = (hd >> 3) * 8 + (wd >> 3); // patch position
    U[lane * 4096 + k * 64 + m] = myu;
  }
}

// ---- Kernel C: att=(A/nz)·U, fold, 1x1 conv, out=corr*x+x, + attn copy ----
__global__ __launch_bounds__(256) void att_fold_corr_k(
    const float* __restrict__ attn, const float* __restrict__ U,
    const float* __restrict__ cw, const float* __restrict__ cb,
    float* __restrict__ out, float* __restrict__ attn_out) {
  __shared__ float Ul[2][4096];
  __shared__ float Ar[4][64];
  const int tid  = threadIdx.x;
  const int lane = tid & 63;
  const int wv   = tid >> 6;
  const int l    = blockIdx.x * 4 + wv;
  const int hq = l >> 6, wq = l & 63;
  const int h = hq * 8 + (lane >> 3), w = wq * 8 + (lane & 7);

  for (int i = tid; i < 1024; i += 256)
    ((fx4*)Ul[0])[i] = ((const fx4*)U)[i];
  __syncthreads();

  float corrv[8];
#pragma unroll 1
  for (int c = 0; c < 8; ++c) {
    if (c < 7)
      for (int i = tid; i < 1024; i += 256)
        ((fx4*)Ul[(c + 1) & 1])[i] = ((const fx4*)(U + (c + 1) * 4096))[i];

    const int aidx = ((c << 12) + l) * 64 + lane;
    float av = attn[aidx];
    attn_out[aidx] = av;                      // output 1: verbatim copy
    unsigned long long nzm = __ballot(av != 0.0f);
    float inv = 1.0f / ((float)__popcll(nzm) + 1e-5f);
    Ar[wv][lane] = av * inv;

    const float* u = Ul[c & 1];
    float s = 0.f;
#pragma unroll
    for (int k = 0; k < 64; ++k)
      s = fmaf(Ar[wv][k], u[k * 64 + lane], s);
    corrv[c] = s;
    __syncthreads();
  }

  const int pix = h * 512 + w;
#pragma unroll
  for (int d = 0; d < 8; ++d) {
    float s = cb[d];
#pragma unroll
    for (int c = 0; c < 8; ++c)
      s = fmaf(corrv[c], cw[d * 8 + c], s);
    float v = out[d * HW + pix];
    out[d * HW + pix] = fmaf(s, v, v);
  }
}

extern "C" void kernel_launch(void* const* d_in, const int* in_sizes, int n_in,
                              void* d_out, int out_size, void* d_ws, size_t ws_size,
                              hipStream_t stream) {
  const float* x    = (const float*)d_in[0];
  const float* attn = (const float*)d_in[1];
  const float* cw   = (const float*)d_in[2];
  const float* cb   = (const float*)d_in[3];
  const float* qw   = (const float*)d_in[4];
  const float* qb   = (const float*)d_in[5];
  float* out = (float*)d_out;

  unsigned short* wpack = (unsigned short*)d_ws;          // 72 KB
  float* U  = (float*)((char*)d_ws + 73728);              // 128 KB
  float* xc = out;                                        // x_conv in out[0:2M]

  pack_w_k<<<dim3(18), dim3(256), 0, stream>>>(cw, wpack);
  conv_mfma_k<<<dim3(512), dim3(512), 0, stream>>>(x, wpack, cb, xc);
  argmax_pool_unfold_k<<<dim3(1024), dim3(256), 0, stream>>>(xc, U);
  att_fold_corr_k<<<dim3(1024), dim3(256), 0, stream>>>(attn, U, qw, qb,
                                                        out, out + 2097152);
}